// Round 7
// baseline (184.080 us; speedup 1.0000x reference)
//
#include <hip/hip_runtime.h>

#define BB 16
#define SS 2048
#define NTOK (BB*SS)
#define FF 512
#define EPSF 1e-5f

#if __has_builtin(__builtin_amdgcn_exp2f)
#define EXP2F(x) __builtin_amdgcn_exp2f(x)
#else
#define EXP2F(x) exp2f(x)
#endif

typedef float v2f __attribute__((ext_vector_type(2)));

// ---------------- ws float layout ----------------
// sm   : [L][64]       fused small mats (exp2-prescaled)   @ 0       (128)
// w1t  : [L][256][24]  FFN pair-records                    @ 128     (12288)
//        {w1 pairs c0..c3 [8], w2 pairs c0..c3 [8], b1 pair [2], pad [6]}
// X0   : [NTOK][4]                                         @ 12416   (131072)
// X1   : [NTOK][4]                                         @ 143488  (131072)
// part : [8][NTOK][8]  per-keyblock partials (padded to 8) @ 274560  (2097152)
// total 2,371,712 floats = 9.5 MB

__device__ __forceinline__ float wred64(float v) {
#pragma unroll
  for (int m = 32; m > 0; m >>= 1) v += __shfl_xor(v, m, 64);
  return v;
}

// sm layout (per layer, stride 64):
// 0:M4[16] (bw2*Wq^T Wk)   16:Bk[16] (-.5 bw2 Wk^T Wk)   32:WVO[16] (Wv*Wo)
// 48:ak[4]  52:bvo[4]  56:ck      where bw2 = bw^2 * log2(e)

// blocks 0..127: build X0 from KEY/VALUE. blocks 128..129: weight prep for layer bid-128.
__global__ __launch_bounds__(256) void prep_kernel(
    const float* __restrict__ KEY, const float* __restrict__ VALUE,
    const float* __restrict__ Wq, const float* __restrict__ bq,
    const float* __restrict__ Wk, const float* __restrict__ bk,
    const float* __restrict__ Wv, const float* __restrict__ bv,
    const float* __restrict__ Wo, const float* __restrict__ bw,
    const float* __restrict__ W1, const float* __restrict__ b1,
    const float* __restrict__ W2,
    float* __restrict__ sm, float* __restrict__ w1t, float* __restrict__ X0)
{
  const int bid = blockIdx.x;
  if (bid < 128) {
    const int gq = bid*256 + threadIdx.x;
    *(float4*)(X0 + (size_t)gq*4) =
        make_float4(KEY[gq*3 + 0], KEY[gq*3 + 1], KEY[gq*3 + 2], VALUE[gq]);
    return;
  }
  const int i = bid - 128;        // layer
  if (threadIdx.x >= 64) return;
  const int lane = threadIdx.x;   // 0..63
  float m4[4][4] = {{0}}, gkk[4][4] = {{0}}, wvo[4][4] = {{0}};
  float akk[4] = {0}, bvo[4] = {0};
  float ck1 = 0.f, ck2 = 0.f;

  for (int h = lane; h < 256; h += 64) {
    float vq[4], vk[4], vv[4], wo4[4];
#pragma unroll
    for (int a = 0; a < 4; ++a) {
      vq[a]  = Wq[(i*4 + a)*256 + h];
      vk[a]  = Wk[(i*4 + a)*256 + h];
      vv[a]  = Wv[(i*4 + a)*256 + h];
      wo4[a] = Wo[(i*256 + h)*4 + a];
    }
    const float bqh = bq[i*256 + h], bkh = bk[i*256 + h], bvh = bv[i*256 + h];
#pragma unroll
    for (int a = 0; a < 4; ++a) {
#pragma unroll
      for (int c = 0; c < 4; ++c) {
        m4[a][c]  = fmaf(vq[a], vk[c], m4[a][c]);
        gkk[a][c] = fmaf(vk[a], vk[c], gkk[a][c]);
        wvo[a][c] = fmaf(vv[a], wo4[c], wvo[a][c]);
      }
      akk[a] = fmaf(vk[a], bqh - bkh, akk[a]);
      bvo[a] = fmaf(bvh, wo4[a], bvo[a]);
    }
    ck1 = fmaf(bqh, bkh, ck1);
    ck2 = fmaf(bkh, bkh, ck2);
  }
#pragma unroll
  for (int a = 0; a < 4; ++a) {
#pragma unroll
    for (int c = 0; c < 4; ++c) {
      m4[a][c]  = wred64(m4[a][c]);
      gkk[a][c] = wred64(gkk[a][c]);
      wvo[a][c] = wred64(wvo[a][c]);
    }
    akk[a] = wred64(akk[a]);
    bvo[a] = wred64(bvo[a]);
  }
  ck1 = wred64(ck1); ck2 = wred64(ck2);

  if (lane == 0) {
    const float bwv = bw[i];
    const float bw2 = bwv * bwv * 1.44269504088896f;   // exp2 prescale
    float* s = sm + i*64;
#pragma unroll
    for (int a = 0; a < 4; ++a) {
#pragma unroll
      for (int c = 0; c < 4; ++c) {
        s[a*4+c]      = bw2 * m4[a][c];
        s[16 + a*4+c] = -0.5f * bw2 * gkk[a][c];
        s[32 + a*4+c] = wvo[a][c];
      }
      s[48+a] = bw2 * akk[a];
      s[52+a] = bvo[a];
    }
    s[56] = bw2 * (ck1 - 0.5f * ck2);
  }
  // FFN pair repack: record fp covers f0=2fp, f1=2fp+1
  for (int fp = lane; fp < 256; fp += 64) {
    const int f0 = 2*fp, f1 = 2*fp + 1;
    float* rec = w1t + (i*256 + fp)*24;
#pragma unroll
    for (int c = 0; c < 4; ++c) {
      rec[c*2 + 0] = W1[(i*4 + c)*FF + f0];
      rec[c*2 + 1] = W1[(i*4 + c)*FF + f1];
      rec[8 + c*2 + 0] = W2[((size_t)i*FF + f0)*4 + c];
      rec[8 + c*2 + 1] = W2[((size_t)i*FF + f1)*4 + c];
    }
    rec[16] = b1[i*FF + f0];
    rec[17] = b1[i*FF + f1];
#pragma unroll
    for (int c = 18; c < 24; ++c) rec[c] = 0.f;
  }
}

// feat record: {P[4], VT[4], R}; query-side constant dropped (cancels in softmax)
__device__ __forceinline__ void compute_feat(const float x[4], const float* __restrict__ s,
                                             float* __restrict__ featrec)
{
  float P[4], VT[4], tk[4];
#pragma unroll
  for (int a = 0; a < 4; ++a) {
    P[a]  = fmaf(s[a*4+3], x[3], fmaf(s[a*4+2], x[2], fmaf(s[a*4+1], x[1], s[a*4+0]*x[0])));
    tk[a] = fmaf(s[16+a*4+3], x[3], fmaf(s[16+a*4+2], x[2], fmaf(s[16+a*4+1], x[1], s[16+a*4+0]*x[0])));
    VT[a] = s[52+a] + fmaf(s[32+3*4+a], x[3], fmaf(s[32+2*4+a], x[2], fmaf(s[32+1*4+a], x[1], s[32+0*4+a]*x[0])));
  }
  float R = s[56];
#pragma unroll
  for (int a = 0; a < 4; ++a) R = fmaf(tk[a] + s[48+a], x[a], R);
  float4* fp = (float4*)featrec;
  fp[0] = make_float4(P[0], P[1], P[2], P[3]);
  fp[1] = make_float4(VT[0], VT[1], VT[2], VT[3]);
  fp[2] = make_float4(R, 0.f, 0.f, 0.f);
}

// attention partials: block covers 256 queries x 256 keys (1024 blocks = 4/CU,
// 4 waves/SIMD for trans/VALU overlap). Key features computed on the fly during
// LDS staging. 4 waves share the 256 queries (4 q/lane, packed pairs for
// v_pk_fma_f32); each wave owns 64 of the 256 staged keys.
// Cross-wave LDS reduction (stride 21, gcd(21,32)=1 -> 2-way aliasing, free).
__global__ __launch_bounds__(256) void attn_kernel(
    const float* __restrict__ X, const float* __restrict__ sm,
    float* __restrict__ part)
{
  __shared__ float smem[256*21];    // 21.5 KB; first 3072 floats double as key buffer
  const int bid = blockIdx.x;
  const int b = bid >> 6;
  const int r = bid & 63;
  const int qg = r >> 3, kb = r & 7;
  const int qbase = (b << 11) + (qg << 8);
  const int kbase = (b << 11) + (kb << 8);
  const int tid = threadIdx.x;
  const int lane = tid & 63, wave = tid >> 6;

  // stage 256 key-feature records, computed from X
  {
    const float4 xk = *(const float4*)(X + (size_t)(kbase + tid)*4);
    float xr[4] = {xk.x, xk.y, xk.z, xk.w};
    float fr[12];
    compute_feat(xr, sm, fr);
    float* dst = smem + tid*12;
    ((float4*)dst)[0] = ((float4*)fr)[0];
    ((float4*)dst)[1] = ((float4*)fr)[1];
    dst[8] = fr[8];
  }

  // query pairs: jp covers queries (2jp, 2jp+1); component-packed for pk_fma
  v2f xq2[2][4], axy[4], azw[4], ad[2];
#pragma unroll
  for (int jp = 0; jp < 2; ++jp) {
    const float4 xa = *(const float4*)(X + (size_t)(qbase + (2*jp  )*64 + lane)*4);
    const float4 xb = *(const float4*)(X + (size_t)(qbase + (2*jp+1)*64 + lane)*4);
    xq2[jp][0] = v2f{xa.x, xb.x};
    xq2[jp][1] = v2f{xa.y, xb.y};
    xq2[jp][2] = v2f{xa.z, xb.z};
    xq2[jp][3] = v2f{xa.w, xb.w};
    ad[jp] = v2f{0.f, 0.f};
  }
#pragma unroll
  for (int j = 0; j < 4; ++j) { axy[j] = v2f{0.f, 0.f}; azw[j] = v2f{0.f, 0.f}; }
  __syncthreads();

  const float* kf = smem + wave*64*12;
#pragma unroll 2
  for (int k = 0; k < 64; ++k) {
    const float* kp = kf + k*12;
    const float4 P  = *(const float4*)kp;
    const float4 VT = *(const float4*)(kp + 4);
    const float R = kp[8];
    const v2f Rv  = v2f{R, R};
    const v2f Px  = v2f{P.x, P.x}, Py = v2f{P.y, P.y};
    const v2f Pz  = v2f{P.z, P.z}, Pw = v2f{P.w, P.w};
    const v2f Vxy = v2f{VT.x, VT.y}, Vzw = v2f{VT.z, VT.w};
#pragma unroll
    for (int jp = 0; jp < 2; ++jp) {
      v2f l = __builtin_elementwise_fma(xq2[jp][0], Px, Rv);
      l = __builtin_elementwise_fma(xq2[jp][1], Py, l);
      l = __builtin_elementwise_fma(xq2[jp][2], Pz, l);
      l = __builtin_elementwise_fma(xq2[jp][3], Pw, l);
      const float e0 = EXP2F(l.x);
      const float e1 = EXP2F(l.y);
      const v2f e0v = v2f{e0, e0}, e1v = v2f{e1, e1};
      axy[2*jp  ] = __builtin_elementwise_fma(e0v, Vxy, axy[2*jp  ]);
      azw[2*jp  ] = __builtin_elementwise_fma(e0v, Vzw, azw[2*jp  ]);
      axy[2*jp+1] = __builtin_elementwise_fma(e1v, Vxy, axy[2*jp+1]);
      azw[2*jp+1] = __builtin_elementwise_fma(e1v, Vzw, azw[2*jp+1]);
      ad[jp] += v2f{e0, e1};
    }
  }
  __syncthreads();     // key buffer dead; reuse LDS for cross-wave reduction
#pragma unroll
  for (int j = 0; j < 4; ++j) {
    float* rr = smem + (j*64 + lane)*21 + wave*5;
    rr[0] = axy[j].x; rr[1] = axy[j].y; rr[2] = azw[j].x;
    rr[3] = azw[j].y; rr[4] = (j & 1) ? ad[j>>1].y : ad[j>>1].x;
  }
  __syncthreads();
  {
    const float* rr = smem + tid*21;
    float s0 = 0.f, s1 = 0.f, s2 = 0.f, s3 = 0.f, s4 = 0.f;
#pragma unroll
    for (int w = 0; w < 4; ++w) {
      s0 += rr[w*5+0]; s1 += rr[w*5+1]; s2 += rr[w*5+2];
      s3 += rr[w*5+3]; s4 += rr[w*5+4];
    }
    float* pp = part + ((size_t)kb * NTOK + qbase + tid)*8;
    *(float4*)pp = make_float4(s0, s1, s2, s3);
    pp[4] = s4;
  }
}

__device__ __forceinline__ void ln4(const float t[4], const float* __restrict__ g,
                                    const float* __restrict__ b, float r[4])
{
  const float m = 0.25f*(t[0]+t[1]+t[2]+t[3]);
  const float d0 = t[0]-m, d1 = t[1]-m, d2 = t[2]-m, d3 = t[3]-m;
  const float v = 0.25f*(d0*d0 + d1*d1 + d2*d2 + d3*d3);
  const float sc = rsqrtf(v + EPSF);
  r[0] = fmaf(d0*sc, g[0], b[0]);
  r[1] = fmaf(d1*sc, g[1], b[1]);
  r[2] = fmaf(d2*sc, g[2], b[2]);
  r[3] = fmaf(d3*sc, g[3], b[3]);
}

// combine: block = 512 thr = 64 tokens x 8 F-chunks; fc k reduces part stripe k.
// FFN processed in f-pairs via v_pk_fma_f32 (w1t pair-records).
__global__ __launch_bounds__(512) void combine_kernel(
    const float* __restrict__ part, const float* __restrict__ Xin,
    const float* __restrict__ w1t,
    const float* __restrict__ bo, const float* __restrict__ g1, const float* __restrict__ be1,
    const float* __restrict__ b2v, const float* __restrict__ g2, const float* __restrict__ be2,
    float* __restrict__ Xout,
    const float* __restrict__ Wfc, const float* __restrict__ bfc,
    float* __restrict__ outp, int last)
{
  const int tok = threadIdx.x & 63, fc = threadIdx.x >> 6;
  const int gq = blockIdx.x*64 + tok;
  __shared__ float redp[8][64][5];
  __shared__ float ress[64][4];
  __shared__ float redf[8][64][4];

  {
    const float* pp = part + ((size_t)fc*NTOK + gq)*8;
    const float4 v = *(const float4*)pp;
    redp[fc][tok][0] = v.x; redp[fc][tok][1] = v.y;
    redp[fc][tok][2] = v.z; redp[fc][tok][3] = v.w;
    redp[fc][tok][4] = pp[4];
  }
  __syncthreads();

  if (fc == 0) {
    float acc[5] = {0,0,0,0,0};
#pragma unroll
    for (int k = 0; k < 8; ++k)
#pragma unroll
      for (int c = 0; c < 5; ++c) acc[c] += redp[k][tok][c];
    const float inv = 1.0f / acc[4];
    const float4 xv = *(const float4*)(Xin + (size_t)gq*4);
    float t[4];
    t[0] = xv.x + fmaf(acc[0], inv, bo[0]);
    t[1] = xv.y + fmaf(acc[1], inv, bo[1]);
    t[2] = xv.z + fmaf(acc[2], inv, bo[2]);
    t[3] = xv.w + fmaf(acc[3], inv, bo[3]);
    float r[4];
    ln4(t, g1, be1, r);
    ress[tok][0] = r[0]; ress[tok][1] = r[1]; ress[tok][2] = r[2]; ress[tok][3] = r[3];
  }
  __syncthreads();

  const v2f r0v = v2f{ress[tok][0], ress[tok][0]};
  const v2f r1v = v2f{ress[tok][1], ress[tok][1]};
  const v2f r2v = v2f{ress[tok][2], ress[tok][2]};
  const v2f r3v = v2f{ress[tok][3], ress[tok][3]};
  v2f f2[4];
#pragma unroll
  for (int c = 0; c < 4; ++c) f2[c] = v2f{0.f, 0.f};
  const float* wt = w1t + (size_t)fc*32*24;
#pragma unroll 4
  for (int fp = 0; fp < 32; ++fp) {
    const float* rec = wt + fp*24;
    const float4 w1a = *(const float4*)rec;         // c0,c1 pairs
    const float4 w1b = *(const float4*)(rec + 4);   // c2,c3 pairs
    const float4 w2a = *(const float4*)(rec + 8);   // w2 c0,c1 pairs
    const float4 w2b = *(const float4*)(rec + 12);  // w2 c2,c3 pairs
    const v2f bv = *(const v2f*)(rec + 16);
    v2f hv = __builtin_elementwise_fma(v2f{w1a.x, w1a.y}, r0v, bv);
    hv = __builtin_elementwise_fma(v2f{w1a.z, w1a.w}, r1v, hv);
    hv = __builtin_elementwise_fma(v2f{w1b.x, w1b.y}, r2v, hv);
    hv = __builtin_elementwise_fma(v2f{w1b.z, w1b.w}, r3v, hv);
    hv = __builtin_elementwise_max(hv, v2f{0.f, 0.f});
    f2[0] = __builtin_elementwise_fma(hv, v2f{w2a.x, w2a.y}, f2[0]);
    f2[1] = __builtin_elementwise_fma(hv, v2f{w2a.z, w2a.w}, f2[1]);
    f2[2] = __builtin_elementwise_fma(hv, v2f{w2b.x, w2b.y}, f2[2]);
    f2[3] = __builtin_elementwise_fma(hv, v2f{w2b.z, w2b.w}, f2[3]);
  }
  redf[fc][tok][0] = f2[0].x + f2[0].y;
  redf[fc][tok][1] = f2[1].x + f2[1].y;
  redf[fc][tok][2] = f2[2].x + f2[2].y;
  redf[fc][tok][3] = f2[3].x + f2[3].y;
  __syncthreads();

  if (fc == 0) {
    float t2[4];
#pragma unroll
    for (int c = 0; c < 4; ++c) {
      float s = b2v[c];
#pragma unroll
      for (int k = 0; k < 8; ++k) s += redf[k][tok][c];
      t2[c] = ress[tok][c] + s;
    }
    float y[4];
    ln4(t2, g2, be2, y);
    if (last) {
      outp[gq] = fmaf(y[3], Wfc[3], fmaf(y[2], Wfc[2], fmaf(y[1], Wfc[1], fmaf(y[0], Wfc[0], bfc[0]))));
    } else {
      *(float4*)(Xout + (size_t)gq*4) = make_float4(y[0], y[1], y[2], y[3]);
    }
  }
}

extern "C" void kernel_launch(void* const* d_in, const int* in_sizes, int n_in,
                              void* d_out, int out_size, void* d_ws, size_t ws_size,
                              hipStream_t stream)
{
  const float* KEY   = (const float*)d_in[0];
  const float* VALUE = (const float*)d_in[1];
  const float* Wq  = (const float*)d_in[2];
  const float* bq  = (const float*)d_in[3];
  const float* Wk  = (const float*)d_in[4];
  const float* bk  = (const float*)d_in[5];
  const float* Wv  = (const float*)d_in[6];
  const float* bv  = (const float*)d_in[7];
  const float* Wo  = (const float*)d_in[8];
  const float* bo  = (const float*)d_in[9];
  const float* bw  = (const float*)d_in[10];
  const float* g1  = (const float*)d_in[11];
  const float* be1 = (const float*)d_in[12];
  const float* W1  = (const float*)d_in[13];
  const float* b1  = (const float*)d_in[14];
  const float* W2  = (const float*)d_in[15];
  const float* b2  = (const float*)d_in[16];
  const float* g2  = (const float*)d_in[17];
  const float* be2 = (const float*)d_in[18];
  const float* Wfc = (const float*)d_in[19];
  const float* bfc = (const float*)d_in[20];
  float* out = (float*)d_out;

  float* w    = (float*)d_ws;
  float* sm   = w;              // 128
  float* w1t  = w + 128;        // 12288
  float* X0   = w + 12416;      // 131072
  float* X1   = w + 143488;     // 131072
  float* part = w + 274560;     // 2097152

  prep_kernel<<<130, 256, 0, stream>>>(KEY, VALUE, Wq, bq, Wk, bk, Wv, bv, Wo, bw,
                                       W1, b1, W2, sm, w1t, X0);

  // layer 0
  attn_kernel<<<1024, 256, 0, stream>>>(X0, sm, part);
  combine_kernel<<<512, 512, 0, stream>>>(part, X0, w1t,
      bo, g1, be1, b2, g2, be2,
      X1, Wfc, bfc, out, 0);

  // layer 1
  attn_kernel<<<1024, 256, 0, stream>>>(X1, sm + 64, part);
  combine_kernel<<<512, 512, 0, stream>>>(part, X1, w1t + 256*24,
      bo + 4, g1 + 4, be1 + 4, b2 + 4, g2 + 4, be2 + 4,
      X0, Wfc, bfc, out, 1);
}